// Round 7
// baseline (17.878 us; speedup 1.0000x reference)
//
#include <hip/hip_runtime.h>
#include <math.h>

// B = 16384 independent 6-var / 9-constraint QPs, 8 IPM iterations.
// Per-thread, fully unrolled, f64 (range safety), rcp+Newton for divides.
// 6x6 KKT reduced analytically: vars 3..5 (diagonal coupling) eliminated ->
// 3x3 Schur complement solved by adjugate (single rcp, no serial pivot chain).
// N_IT=8: absmax 0.03125 vs threshold 0.226 (7x margin); 7 iters would be ~5x
// worse -> stay at 8.
// This round: one rcp per constraint (rcp(s*lam) -> invs,invl), rp folded out
// of g (the +s-s cancels), raw v_rcp_f64 for alpha (0.99 slack covers 1e-8).
//
// Qmod nonzeros: [0][0]=4.001 [0][1]=-4 [1][0]=-4 [1][1]=4.001, diag 2..5 = 0.001
// R rows 0..5 = -e_i ; rows 6..8 = a_j:
//   a0 = [-1, 1,-1, 1, 0, 0]
//   a1 = [ 1,-1,-1, 0, 1, 0]
//   a2 = [ 1, 1, 0, 0, 0, 1]

#define N_IT 8

__device__ __forceinline__ double drcp1(double x) {   // ~2^-28 rel err
    double r = __builtin_amdgcn_rcp(x);
    double e = fma(-x, r, 1.0);
    return fma(r, e, r);
}

__global__ __launch_bounds__(64) void qp_kernel(const float* __restrict__ vk,
                                                const float* __restrict__ mup,
                                                float* __restrict__ out, int B) {
    int i = blockIdx.x * blockDim.x + threadIdx.x;
    if (i >= B) return;

    const double v  = (double)vk[i];
    const double mu = (double)mup[0];
    const double beta = -v;
    const double vu = v + 2.0;

    // p = [3v+2, -(3v+2), mu, 1, 1, 1]
    double p0 = 3.0 * v + 2.0;
    double p1 = -p0;
    double p2 = mu;
    // h = [0 x6, vu, -vu, mu]
    double h6 = vu, h7 = -vu, h8 = mu;

    double z[6] = {0.0, 0.0, 0.0, 0.0, 0.0, 0.0};
    double s[9], lam[9];
#pragma unroll
    for (int k = 0; k < 9; ++k) { s[k] = 1.0; lam[k] = 1.0; }

    for (int it = 0; it < N_IT; ++it) {
        // ---- Qz + p ----
        double Qp0 = 4.001 * z[0] - 4.0 * z[1] + p0;
        double Qp1 = -4.0 * z[0] + 4.001 * z[1] + p1;
        double Qp2 = 0.001 * z[2] + p2;
        double Qp3 = 0.001 * z[3] + 1.0;
        double Qp4 = 0.001 * z[4] + 1.0;
        double Qp5 = 0.001 * z[5] + 1.0;

        // Rz - h  (rows 0..5: -z_k; rows 6..8: a_j z - h_j)
        double rzh[9];
        rzh[0] = -z[0]; rzh[1] = -z[1]; rzh[2] = -z[2];
        rzh[3] = -z[3]; rzh[4] = -z[4]; rzh[5] = -z[5];
        rzh[6] = -z[0] + z[1] - z[2] + z[3] - h6;
        rzh[7] =  z[0] - z[1] - z[2] + z[4] - h7;
        rzh[8] =  z[0] + z[1] + z[5] - h8;

        // ---- products, barrier parameter, fused reciprocals ----
        double pr[9];
        double dot = 0.0;
#pragma unroll
        for (int k = 0; k < 9; ++k) { pr[k] = s[k] * lam[k]; dot += pr[k]; }
        double mip = (0.1 / 9.0) * dot;

        double invs[9], invl[9], W[9], g[9], u[9];
#pragma unroll
        for (int k = 0; k < 9; ++k) {
            double ipr = drcp1(pr[k]);          // 1/(s*lam)
            invl[k] = s[k]   * ipr;             // 1/lam
            invs[k] = lam[k] * ipr;             // 1/s
            W[k]    = lam[k] * invs[k];         // lam/s
            g[k]    = fma(mip, invl[k], rzh[k]);     // rp + mip/lam - s (s cancels)
            u[k]    = fma(W[k], g[k], lam[k]);       // lam + W*g
        }
        double w6 = W[6], w7 = W[7], w8 = W[8];

        // rhs = -(Qz+p) - R^T u ; (R^T u)_k = -u_k + sum_j a_j[k] u_{6+j}
        double rhs0 = -Qp0 + u[0] + u[6] - u[7] - u[8];
        double rhs1 = -Qp1 + u[1] - u[6] + u[7] - u[8];
        double rhs2 = -Qp2 + u[2] + u[6] + u[7];
        double rhs3 = -Qp3 + u[3] - u[6];
        double rhs4 = -Qp4 + u[4] - u[7];
        double rhs5 = -Qp5 + u[5] - u[8];

        // ---- eliminate z3..z5 (diagonal block): d_j = 0.001+W[3+j]+w_j ----
        double dp3 = 0.001 + W[3], dp4 = 0.001 + W[4], dp5 = 0.001 + W[5];
        double d3 = dp3 + w6, d4 = dp4 + w7, d5 = dp5 + w8;
        double id3 = drcp1(d3), id4 = drcp1(d4), id5 = drcp1(d5);
        double e6 = w6 * id3, e7 = w7 * id4, e8 = w8 * id5;   // w_j/d_j
        double c6 = w6 * dp3 * id3;   // hat-c_j = w_j dp_j / d_j (all-positive)
        double c7 = w7 * dp4 * id4;
        double c8 = w8 * dp5 * id5;
        double q6 = e6 * rhs3, q7 = e7 * rhs4, q8 = e8 * rhs5;

        // reduced rhs (3): rhs012 - sum_j q_j a'_j
        double r0 = rhs0 + q6 - q7 - q8;
        double r1 = rhs1 - q6 + q7 - q8;
        double r2 = rhs2 + q6 + q7;

        // reduced matrix S = Q3 + diag(W0..2) + sum_j c_j a'_j a'_j^T
        double csum = c6 + c7 + c8;
        double S00 = 4.001 + W[0] + csum;
        double S01 = -4.0 - c6 - c7 + c8;
        double S02 = c6 - c7;
        double S11 = 4.001 + W[1] + csum;
        double S12 = -c6 + c7;
        double S22 = 0.001 + W[2] + c6 + c7;

        // ---- 3x3 symmetric solve by adjugate (1 rcp, max ILP) ----
        double c00 = fma(S11, S22, -S12 * S12);
        double c01 = fma(S02, S12, -S01 * S22);
        double c02 = fma(S01, S12, -S02 * S11);
        double c11 = fma(S00, S22, -S02 * S02);
        double c12 = fma(S01, S02, -S00 * S12);
        double c22 = fma(S00, S11, -S01 * S01);
        double det = fma(S00, c00, fma(S01, c01, S02 * c02));
        det = fmax(det, 1e-280);      // S is SPD; guard vs rounding
        double idet = drcp1(det);
        double x0 = fma(c00, r0, fma(c01, r1, c02 * r2)) * idet;
        double x1 = fma(c01, r0, fma(c11, r1, c12 * r2)) * idet;
        double x2 = fma(c02, r0, fma(c12, r1, c22 * r2)) * idet;

        // back-substitute z3..z5
        double a6x = -x0 + x1 - x2;
        double a7x =  x0 - x1 - x2;
        double a8x =  x0 + x1;
        double dz3 = fma(-e6, a6x, rhs3 * id3);
        double dz4 = fma(-e7, a7x, rhs4 * id4);
        double dz5 = fma(-e8, a8x, rhs5 * id5);

        // ---- dlam, ds ----
        double Rdz[9];
        Rdz[0] = -x0; Rdz[1] = -x1; Rdz[2] = -x2;
        Rdz[3] = -dz3; Rdz[4] = -dz4; Rdz[5] = -dz5;
        Rdz[6] = a6x + dz3;
        Rdz[7] = a7x + dz4;
        Rdz[8] = a8x + dz5;

        double dl[9], ds[9];
#pragma unroll
        for (int k = 0; k < 9; ++k) {
            dl[k] = W[k] * (Rdz[k] + g[k]);
            double comp = mip - pr[k];                    // mip - s*lam (reuse pr)
            ds[k] = fma(-s[k], dl[k], comp) * invl[k];
        }

        // ---- step length: alpha = 0.99*min(1, 1/max_k(-dx_k*inv_x_k)) ----
        double M = 1e-300;   // clamp: M<=0 => alpha=0.99 (matches branchy form)
#pragma unroll
        for (int k = 0; k < 9; ++k) {
            M = fmax(M, -ds[k] * invs[k]);
            M = fmax(M, -dl[k] * invl[k]);
        }
        // raw v_rcp_f64 (~1e-8 rel err) is safe: 0.99 factor gives 1% slack
        double alpha = 0.99 * fmin(1.0, __builtin_amdgcn_rcp(M));

        z[0] = fma(alpha, x0, z[0]);
        z[1] = fma(alpha, x1, z[1]);
        z[2] = fma(alpha, x2, z[2]);
        z[3] = fma(alpha, dz3, z[3]);
        z[4] = fma(alpha, dz4, z[4]);
        z[5] = fma(alpha, dz5, z[5]);
#pragma unroll
        for (int k = 0; k < 9; ++k) {
            s[k]   = fma(alpha, ds[k], s[k]);
            lam[k] = fma(alpha, dl[k], lam[k]);
        }
    }

    // ---- cost = 0.5 z'Qz + p'z + beta^2 ----
    double zQz = 4.001 * (z[0] * z[0] + z[1] * z[1]) - 8.0 * z[0] * z[1]
               + 0.001 * (z[2] * z[2] + z[3] * z[3] + z[4] * z[4] + z[5] * z[5]);
    double pz = p0 * z[0] + p1 * z[1] + p2 * z[2] + z[3] + z[4] + z[5];
    double cost = 0.5 * zQz + pz + beta * beta;

    out[i] = (float)cost;
}

extern "C" void kernel_launch(void* const* d_in, const int* in_sizes, int n_in,
                              void* d_out, int out_size, void* d_ws, size_t ws_size,
                              hipStream_t stream) {
    const float* vk = (const float*)d_in[0];
    const float* mu = (const float*)d_in[1];
    float* out = (float*)d_out;
    int B = in_sizes[0];
    int block = 64;
    int grid = (B + block - 1) / block;
    hipLaunchKernelGGL(qp_kernel, dim3(grid), dim3(block), 0, stream, vk, mu, out, B);
}

// Round 8
// 11.771 us; speedup vs baseline: 1.5188x; 1.5188x over previous
//
#include <hip/hip_runtime.h>
#include <math.h>

// B = 16384 independent 6-var / 9-constraint QPs, 8 IPM iterations.
// Per-thread, fully unrolled, f64 (range safety), rcp+Newton for divides.
// 6x6 KKT reduced analytically: vars 3..5 (diagonal coupling) eliminated ->
// 3x3 Schur complement solved by adjugate (single rcp, no serial pivot chain).
// N_IT=8: absmax 0.03125 vs threshold 0.226 (7x margin); 7 iters ~5x worse.
//
// ROUND 8 = ROUND 6 STRUCTURE (12.2us) + safe deltas only. Round 7's pr-fused
// rcp (17.9us) extended pr[9]'s live range across the body + serialized the
// rcp inputs -> suspected VGPR-cliff/spill; reverted. Deltas kept:
//   - __launch_bounds__(64,1): occupancy is grid-limited to 1 wave/SIMD anyway;
//     allow full VGPR budget so nothing can spill.
//   - g = fma(mip, invl, Rz-h)  (rp's +s-s cancels structurally)
//   - tree reductions for the mip-dot and the step-length max (chain 18->5)
//   - raw v_rcp_f64 for alpha (1e-8 err << 1% slack of the 0.99 factor)
//
// Qmod nonzeros: [0][0]=4.001 [0][1]=-4 [1][0]=-4 [1][1]=4.001, diag 2..5 = 0.001
// R rows 0..5 = -e_i ; rows 6..8 = a_j:
//   a0 = [-1, 1,-1, 1, 0, 0]
//   a1 = [ 1,-1,-1, 0, 1, 0]
//   a2 = [ 1, 1, 0, 0, 0, 1]

#define N_IT 8

__device__ __forceinline__ double drcp1(double x) {   // ~2^-28 rel err
    double r = __builtin_amdgcn_rcp(x);
    double e = fma(-x, r, 1.0);
    return fma(r, e, r);
}

__global__ __launch_bounds__(64, 1) void qp_kernel(const float* __restrict__ vk,
                                                   const float* __restrict__ mup,
                                                   float* __restrict__ out, int B) {
    int i = blockIdx.x * blockDim.x + threadIdx.x;
    if (i >= B) return;

    const double v  = (double)vk[i];
    const double mu = (double)mup[0];
    const double beta = -v;
    const double vu = v + 2.0;

    // p = [3v+2, -(3v+2), mu, 1, 1, 1]
    double p0 = 3.0 * v + 2.0;
    double p1 = -p0;
    double p2 = mu;
    // h = [0 x6, vu, -vu, mu]
    double h6 = vu, h7 = -vu, h8 = mu;

    double z[6] = {0.0, 0.0, 0.0, 0.0, 0.0, 0.0};
    double s[9], lam[9];
#pragma unroll
    for (int k = 0; k < 9; ++k) { s[k] = 1.0; lam[k] = 1.0; }

    for (int it = 0; it < N_IT; ++it) {
        // ---- Qz + p ----
        double Qp0 = 4.001 * z[0] - 4.0 * z[1] + p0;
        double Qp1 = -4.0 * z[0] + 4.001 * z[1] + p1;
        double Qp2 = 0.001 * z[2] + p2;
        double Qp3 = 0.001 * z[3] + 1.0;
        double Qp4 = 0.001 * z[4] + 1.0;
        double Qp5 = 0.001 * z[5] + 1.0;

        // Rz - h  (rows 0..5: -z_k; rows 6..8: a_j z - h_j)
        double rzh[9];
        rzh[0] = -z[0]; rzh[1] = -z[1]; rzh[2] = -z[2];
        rzh[3] = -z[3]; rzh[4] = -z[4]; rzh[5] = -z[5];
        rzh[6] = -z[0] + z[1] - z[2] + z[3] - h6;
        rzh[7] =  z[0] - z[1] - z[2] + z[4] - h7;
        rzh[8] =  z[0] + z[1] + z[5] - h8;

        // ---- barrier parameter (tree-summed dot) ----
        double sl0 = s[0] * lam[0], sl1 = s[1] * lam[1], sl2 = s[2] * lam[2];
        double sl3 = s[3] * lam[3], sl4 = s[4] * lam[4], sl5 = s[5] * lam[5];
        double sl6 = s[6] * lam[6], sl7 = s[7] * lam[7], sl8 = s[8] * lam[8];
        double dA = (sl0 + sl1) + (sl2 + sl3);
        double dB = (sl4 + sl5) + (sl6 + sl7);
        double mip = (0.1 / 9.0) * ((dA + dB) + sl8);

        // ---- invs, invl, W, g, u (independent rcp chains) ----
        double invs[9], invl[9], W[9], g[9], u[9];
#pragma unroll
        for (int k = 0; k < 9; ++k) {
            invs[k] = drcp1(s[k]);
            invl[k] = drcp1(lam[k]);
            W[k]    = lam[k] * invs[k];
            g[k]    = fma(mip, invl[k], rzh[k]);   // rp + mip/lam - s (s cancels)
            u[k]    = fma(W[k], g[k], lam[k]);     // lam + W*g
        }
        double w6 = W[6], w7 = W[7], w8 = W[8];

        // rhs = -(Qz+p) - R^T u ; (R^T u)_k = -u_k + sum_j a_j[k] u_{6+j}
        double rhs0 = -Qp0 + u[0] + u[6] - u[7] - u[8];
        double rhs1 = -Qp1 + u[1] - u[6] + u[7] - u[8];
        double rhs2 = -Qp2 + u[2] + u[6] + u[7];
        double rhs3 = -Qp3 + u[3] - u[6];
        double rhs4 = -Qp4 + u[4] - u[7];
        double rhs5 = -Qp5 + u[5] - u[8];

        // ---- eliminate z3..z5 (diagonal block): d_j = 0.001+W[3+j]+w_j ----
        double dp3 = 0.001 + W[3], dp4 = 0.001 + W[4], dp5 = 0.001 + W[5];
        double d3 = dp3 + w6, d4 = dp4 + w7, d5 = dp5 + w8;
        double id3 = drcp1(d3), id4 = drcp1(d4), id5 = drcp1(d5);
        double e6 = w6 * id3, e7 = w7 * id4, e8 = w8 * id5;   // w_j/d_j
        double c6 = w6 * dp3 * id3;   // hat-c_j = w_j dp_j / d_j (all-positive)
        double c7 = w7 * dp4 * id4;
        double c8 = w8 * dp5 * id5;
        double q6 = e6 * rhs3, q7 = e7 * rhs4, q8 = e8 * rhs5;

        // reduced rhs (3): rhs012 - sum_j q_j a'_j
        double r0 = rhs0 + q6 - q7 - q8;
        double r1 = rhs1 - q6 + q7 - q8;
        double r2 = rhs2 + q6 + q7;

        // reduced matrix S = Q3 + diag(W0..2) + sum_j c_j a'_j a'_j^T
        double csum = c6 + c7 + c8;
        double S00 = 4.001 + W[0] + csum;
        double S01 = -4.0 - c6 - c7 + c8;
        double S02 = c6 - c7;
        double S11 = 4.001 + W[1] + csum;
        double S12 = -c6 + c7;
        double S22 = 0.001 + W[2] + c6 + c7;

        // ---- 3x3 symmetric solve by adjugate (1 rcp, max ILP) ----
        double c00 = fma(S11, S22, -S12 * S12);
        double c01 = fma(S02, S12, -S01 * S22);
        double c02 = fma(S01, S12, -S02 * S11);
        double c11 = fma(S00, S22, -S02 * S02);
        double c12 = fma(S01, S02, -S00 * S12);
        double c22 = fma(S00, S11, -S01 * S01);
        double det = fma(S00, c00, fma(S01, c01, S02 * c02));
        det = fmax(det, 1e-280);      // S is SPD; guard vs rounding
        double idet = drcp1(det);
        double x0 = fma(c00, r0, fma(c01, r1, c02 * r2)) * idet;
        double x1 = fma(c01, r0, fma(c11, r1, c12 * r2)) * idet;
        double x2 = fma(c02, r0, fma(c12, r1, c22 * r2)) * idet;

        // back-substitute z3..z5
        double a6x = -x0 + x1 - x2;
        double a7x =  x0 - x1 - x2;
        double a8x =  x0 + x1;
        double dz3 = fma(-e6, a6x, rhs3 * id3);
        double dz4 = fma(-e7, a7x, rhs4 * id4);
        double dz5 = fma(-e8, a8x, rhs5 * id5);

        // ---- dlam, ds ----
        double Rdz[9];
        Rdz[0] = -x0; Rdz[1] = -x1; Rdz[2] = -x2;
        Rdz[3] = -dz3; Rdz[4] = -dz4; Rdz[5] = -dz5;
        Rdz[6] = a6x + dz3;
        Rdz[7] = a7x + dz4;
        Rdz[8] = a8x + dz5;

        double dl[9], ds[9];
#pragma unroll
        for (int k = 0; k < 9; ++k) {
            dl[k] = W[k] * (Rdz[k] + g[k]);
            double comp = fma(-s[k], lam[k], mip);
            ds[k] = fma(-s[k], dl[k], comp) * invl[k];
        }

        // ---- step length: alpha = 0.99*min(1, 1/max_k(-dx_k*inv_x_k)) ----
        double m0 = fmax(-ds[0] * invs[0], -dl[0] * invl[0]);
        double m1 = fmax(-ds[1] * invs[1], -dl[1] * invl[1]);
        double m2 = fmax(-ds[2] * invs[2], -dl[2] * invl[2]);
        double m3 = fmax(-ds[3] * invs[3], -dl[3] * invl[3]);
        double m4 = fmax(-ds[4] * invs[4], -dl[4] * invl[4]);
        double m5 = fmax(-ds[5] * invs[5], -dl[5] * invl[5]);
        double m6 = fmax(-ds[6] * invs[6], -dl[6] * invl[6]);
        double m7 = fmax(-ds[7] * invs[7], -dl[7] * invl[7]);
        double m8 = fmax(-ds[8] * invs[8], -dl[8] * invl[8]);
        double MA = fmax(fmax(m0, m1), fmax(m2, m3));
        double MB = fmax(fmax(m4, m5), fmax(m6, m7));
        double M  = fmax(fmax(MA, MB), fmax(m8, 1e-300));
        // raw v_rcp_f64 (~1e-8 rel err) safe: 0.99 factor gives 1% slack
        double alpha = 0.99 * fmin(1.0, __builtin_amdgcn_rcp(M));

        z[0] = fma(alpha, x0, z[0]);
        z[1] = fma(alpha, x1, z[1]);
        z[2] = fma(alpha, x2, z[2]);
        z[3] = fma(alpha, dz3, z[3]);
        z[4] = fma(alpha, dz4, z[4]);
        z[5] = fma(alpha, dz5, z[5]);
#pragma unroll
        for (int k = 0; k < 9; ++k) {
            s[k]   = fma(alpha, ds[k], s[k]);
            lam[k] = fma(alpha, dl[k], lam[k]);
        }
    }

    // ---- cost = 0.5 z'Qz + p'z + beta^2 ----
    double zQz = 4.001 * (z[0] * z[0] + z[1] * z[1]) - 8.0 * z[0] * z[1]
               + 0.001 * (z[2] * z[2] + z[3] * z[3] + z[4] * z[4] + z[5] * z[5]);
    double pz = p0 * z[0] + p1 * z[1] + p2 * z[2] + z[3] + z[4] + z[5];
    double cost = 0.5 * zQz + pz + beta * beta;

    out[i] = (float)cost;
}

extern "C" void kernel_launch(void* const* d_in, const int* in_sizes, int n_in,
                              void* d_out, int out_size, void* d_ws, size_t ws_size,
                              hipStream_t stream) {
    const float* vk = (const float*)d_in[0];
    const float* mu = (const float*)d_in[1];
    float* out = (float*)d_out;
    int B = in_sizes[0];
    int block = 64;
    int grid = (B + block - 1) / block;
    hipLaunchKernelGGL(qp_kernel, dim3(grid), dim3(block), 0, stream, vk, mu, out, B);
}